// Round 1
// baseline (325.757 us; speedup 1.0000x reference)
//
#include <hip/hip_runtime.h>
#include <math.h>

#define N_NODES 50000
#define N_EDGES 800000
#define IN_DIM 64
#define H_HEADS 4
#define D_HEAD 16
#define NT_TYPES 2
#define ET_TYPES 2
#define HD 64                       // H*D
#define NB_SCAN ((N_NODES + 255) / 256)   // 196

// ---------------------------------------------------------------------------
// Kernel 1: per-node projections.
//   k,q,v = x @ W{k,q,v}[ntype]  (64x64)
//   katt[et][n][h*16+f] = sum_d k[n][h][d] * Ratt[h][et][d][f]
//   vmsg[et][n][h*16+f] = sum_d v[n][h][d] * Rmsg[h][et][d][f]
// One 64-lane wave per node, 4 nodes per 256-thread block.
// ---------------------------------------------------------------------------
__global__ __launch_bounds__(256) void node_proj_kernel(
    const float* __restrict__ x, const float* __restrict__ Wk,
    const float* __restrict__ Wq, const float* __restrict__ Wv,
    const float* __restrict__ Ratt, const float* __restrict__ Rmsg,
    const int* __restrict__ ntype,
    float* __restrict__ q, float* __restrict__ katt, float* __restrict__ vmsg) {
  const int wave = threadIdx.x >> 6;
  const int lane = threadIdx.x & 63;
  const int n = blockIdx.x * 4 + wave;
  const bool valid = (n < N_NODES);

  __shared__ float xs[4][64];
  __shared__ float ks[4][64];
  __shared__ float vs[4][64];

  int t = 0;
  if (valid) {
    t = ntype[n];
    xs[wave][lane] = x[(size_t)n * 64 + lane];
  }
  __syncthreads();

  if (valid) {
    const float* wk = Wk + (size_t)t * 4096;
    const float* wq = Wq + (size_t)t * 4096;
    const float* wv = Wv + (size_t)t * 4096;
    float ak = 0.f, aq = 0.f, av = 0.f;
#pragma unroll 8
    for (int i = 0; i < 64; ++i) {
      float xi = xs[wave][i];
      ak = fmaf(xi, wk[i * 64 + lane], ak);
      aq = fmaf(xi, wq[i * 64 + lane], aq);
      av = fmaf(xi, wv[i * 64 + lane], av);
    }
    q[(size_t)n * 64 + lane] = aq;
    ks[wave][lane] = ak;
    vs[wave][lane] = av;
  }
  __syncthreads();

  if (valid) {
    const int hh = lane >> 4;
    const int f = lane & 15;
#pragma unroll
    for (int et = 0; et < ET_TYPES; ++et) {
      const float* ra = Ratt + ((size_t)(hh * ET_TYPES + et)) * 256;
      const float* rm = Rmsg + ((size_t)(hh * ET_TYPES + et)) * 256;
      float sa = 0.f, sm = 0.f;
#pragma unroll
      for (int d0 = 0; d0 < 16; ++d0) {
        float kd = ks[wave][hh * 16 + d0];
        float vd = vs[wave][hh * 16 + d0];
        sa = fmaf(kd, ra[d0 * 16 + f], sa);
        sm = fmaf(vd, rm[d0 * 16 + f], sm);
      }
      size_t base = ((size_t)et * N_NODES + n) * 64 + lane;
      katt[base] = sa;
      vmsg[base] = sm;
    }
  }
}

// ---------------------------------------------------------------------------
// CSR build: count degrees, 3-kernel scan, fill packed edge records.
// ---------------------------------------------------------------------------
__global__ void count_deg_kernel(const int* __restrict__ dst, int* __restrict__ deg) {
  int e = blockIdx.x * 256 + threadIdx.x;
  if (e < N_EDGES) atomicAdd(&deg[dst[e]], 1);
}

__global__ void block_sums_kernel(const int* __restrict__ deg, int* __restrict__ bsums) {
  __shared__ int sh[256];
  int i = blockIdx.x * 256 + threadIdx.x;
  sh[threadIdx.x] = (i < N_NODES) ? deg[i] : 0;
  __syncthreads();
  for (int off = 128; off > 0; off >>= 1) {
    if (threadIdx.x < off) sh[threadIdx.x] += sh[threadIdx.x + off];
    __syncthreads();
  }
  if (threadIdx.x == 0) bsums[blockIdx.x] = sh[0];
}

__global__ void scan_sums_kernel(int* __restrict__ bsums) {
  __shared__ int sh[256];
  int t = threadIdx.x;
  sh[t] = (t < NB_SCAN) ? bsums[t] : 0;
  __syncthreads();
  for (int off = 1; off < 256; off <<= 1) {
    int v = (t >= off) ? sh[t - off] : 0;
    __syncthreads();
    sh[t] += v;
    __syncthreads();
  }
  if (t < NB_SCAN) bsums[t] = (t ? sh[t - 1] : 0);  // exclusive
}

__global__ void scan_final_kernel(const int* __restrict__ deg, const int* __restrict__ bsums,
                                  int* __restrict__ rowstart, int* __restrict__ cursor) {
  __shared__ int sh[256];
  int i = blockIdx.x * 256 + threadIdx.x;
  int t = threadIdx.x;
  sh[t] = (i < N_NODES) ? deg[i] : 0;
  __syncthreads();
  for (int off = 1; off < 256; off <<= 1) {
    int v = (t >= off) ? sh[t - off] : 0;
    __syncthreads();
    sh[t] += v;
    __syncthreads();
  }
  if (i < N_NODES) {
    int excl = (t ? sh[t - 1] : 0) + bsums[blockIdx.x];
    rowstart[i] = excl;
    cursor[i] = excl;
  }
}

__global__ void fill_csr_kernel(const int* __restrict__ src, const int* __restrict__ dst,
                                const int* __restrict__ etype, int* __restrict__ cursor,
                                int* __restrict__ csr) {
  int e = blockIdx.x * 256 + threadIdx.x;
  if (e < N_EDGES) {
    int d = dst[e];
    int pos = atomicAdd(&cursor[d], 1);
    csr[pos] = src[e] | (etype[e] << 16);  // src < 65536, et in {0,1}
  }
}

// ---------------------------------------------------------------------------
// Kernel 2: per-dst-node online-softmax aggregation + typed output linear +
// sigmoid-skip blend. One 64-lane wave per node; lane l = (head=l>>4, f=l&15).
// ---------------------------------------------------------------------------
__global__ __launch_bounds__(256) void aggregate_kernel(
    const float* __restrict__ q, const float* __restrict__ katt,
    const float* __restrict__ vmsg, const float* __restrict__ x,
    const float* __restrict__ Wa, const float* __restrict__ pri,
    const float* __restrict__ skip, const int* __restrict__ ntype,
    const int* __restrict__ rowstart, const int* __restrict__ deg,
    const int* __restrict__ csr, float* __restrict__ out) {
  const int wave = threadIdx.x >> 6;
  const int lane = threadIdx.x & 63;
  const int n = blockIdx.x * 4 + wave;
  const bool valid = (n < N_NODES);

  __shared__ float hs[4][64];

  int t = 0;
  if (valid) {
    t = ntype[n];
    const int hh = lane >> 4;
    const float qd = q[(size_t)n * 64 + lane];
    const float p0 = pri[hh * ET_TYPES + 0] * 0.25f;  // /sqrt(16)
    const float p1 = pri[hh * ET_TYPES + 1] * 0.25f;
    const int start = rowstart[n];
    const int cnt = deg[n];

    float mrun = -INFINITY, srun = 0.f, acc = 0.f;
    for (int j = 0; j < cnt; ++j) {
      int pk = csr[start + j];
      int s = pk & 0xFFFF;
      int et = pk >> 16;
      size_t base = ((size_t)et * N_NODES + s) * 64 + lane;
      float kw = katt[base];
      float mv = vmsg[base];
      float p = kw * qd;
      p += __shfl_xor(p, 1, 16);
      p += __shfl_xor(p, 2, 16);
      p += __shfl_xor(p, 4, 16);
      p += __shfl_xor(p, 8, 16);
      float a = p * (et ? p1 : p0);
      float nm = fmaxf(mrun, a);
      float e1 = __expf(mrun - nm);   // 0 on first edge (mrun = -inf)
      float e2 = __expf(a - nm);
      srun = srun * e1 + e2;
      acc = acc * e1 + mv * e2;
      mrun = nm;
    }
    hs[wave][lane] = (srun > 0.f) ? (acc / srun) : 0.f;
  }
  __syncthreads();

  if (valid) {
    const float* wa = Wa + (size_t)t * 4096;
    float acc2 = 0.f;
#pragma unroll 8
    for (int i = 0; i < 64; ++i) acc2 = fmaf(hs[wave][i], wa[i * 64 + lane], acc2);
    float alpha = 1.f / (1.f + __expf(-skip[t]));
    size_t o = (size_t)n * 64 + lane;
    out[o] = acc2 * alpha + x[o] * (1.f - alpha);
  }
}

// ---------------------------------------------------------------------------
extern "C" void kernel_launch(void* const* d_in, const int* in_sizes, int n_in,
                              void* d_out, int out_size, void* d_ws, size_t ws_size,
                              hipStream_t stream) {
  const float* x    = (const float*)d_in[0];
  const float* Wk   = (const float*)d_in[1];
  const float* Wq   = (const float*)d_in[2];
  const float* Wv   = (const float*)d_in[3];
  const float* Wa   = (const float*)d_in[4];
  const float* Ratt = (const float*)d_in[5];
  const float* Rmsg = (const float*)d_in[6];
  const float* pri  = (const float*)d_in[7];
  const float* skip = (const float*)d_in[8];
  const int* ntype  = (const int*)d_in[9];
  const int* etype  = (const int*)d_in[10];
  const int* src    = (const int*)d_in[11];
  const int* dst    = (const int*)d_in[12];
  float* out = (float*)d_out;

  // workspace layout
  float* q    = (float*)d_ws;                        // N*64
  float* katt = q + (size_t)N_NODES * 64;            // ET*N*64
  float* vmsg = katt + (size_t)ET_TYPES * N_NODES * 64;
  int* rowstart = (int*)(vmsg + (size_t)ET_TYPES * N_NODES * 64);  // N
  int* deg      = rowstart + N_NODES;                // N
  int* cursor   = deg + N_NODES;                     // N
  int* csr      = cursor + N_NODES;                  // E
  int* bsums    = csr + N_EDGES;                     // NB_SCAN

  hipMemsetAsync(deg, 0, N_NODES * sizeof(int), stream);

  node_proj_kernel<<<(N_NODES + 3) / 4, 256, 0, stream>>>(
      x, Wk, Wq, Wv, Ratt, Rmsg, ntype, q, katt, vmsg);

  count_deg_kernel<<<(N_EDGES + 255) / 256, 256, 0, stream>>>(dst, deg);
  block_sums_kernel<<<NB_SCAN, 256, 0, stream>>>(deg, bsums);
  scan_sums_kernel<<<1, 256, 0, stream>>>(bsums);
  scan_final_kernel<<<NB_SCAN, 256, 0, stream>>>(deg, bsums, rowstart, cursor);
  fill_csr_kernel<<<(N_EDGES + 255) / 256, 256, 0, stream>>>(src, dst, etype, cursor, csr);

  aggregate_kernel<<<(N_NODES + 3) / 4, 256, 0, stream>>>(
      q, katt, vmsg, x, Wa, pri, skip, ntype, rowstart, deg, csr, out);
}

// Round 2
// 275.085 us; speedup vs baseline: 1.1842x; 1.1842x over previous
//
#include <hip/hip_runtime.h>
#include <math.h>

#define N_NODES 50000
#define N_EDGES 800000
#define IN_DIM 64
#define H_HEADS 4
#define D_HEAD 16
#define NT_TYPES 2
#define ET_TYPES 2
#define HD 64
#define NB_SCAN ((N_NODES + 255) / 256)   // 196

// ---------------------------------------------------------------------------
// Kernel 1: per-node projections.
//   k,q,v = x @ W{k,q,v}[ntype]  (64x64)
//   kv[et][n][lane] = float2( katt, vmsg )   (interleaved for 1-load gathers)
// One 64-lane wave per node, 4 nodes per 256-thread block.
// ---------------------------------------------------------------------------
__global__ __launch_bounds__(256) void node_proj_kernel(
    const float* __restrict__ x, const float* __restrict__ Wk,
    const float* __restrict__ Wq, const float* __restrict__ Wv,
    const float* __restrict__ Ratt, const float* __restrict__ Rmsg,
    const int* __restrict__ ntype,
    float* __restrict__ q, float2* __restrict__ kv) {
  const int wave = threadIdx.x >> 6;
  const int lane = threadIdx.x & 63;
  const int n = blockIdx.x * 4 + wave;
  const bool valid = (n < N_NODES);

  __shared__ float xs[4][64];
  __shared__ float ks[4][64];
  __shared__ float vs[4][64];

  int t = 0;
  if (valid) {
    t = ntype[n];
    xs[wave][lane] = x[(size_t)n * 64 + lane];
  }
  __syncthreads();

  if (valid) {
    const float* wk = Wk + (size_t)t * 4096;
    const float* wq = Wq + (size_t)t * 4096;
    const float* wv = Wv + (size_t)t * 4096;
    float ak = 0.f, aq = 0.f, av = 0.f;
#pragma unroll 8
    for (int i = 0; i < 64; ++i) {
      float xi = xs[wave][i];
      ak = fmaf(xi, wk[i * 64 + lane], ak);
      aq = fmaf(xi, wq[i * 64 + lane], aq);
      av = fmaf(xi, wv[i * 64 + lane], av);
    }
    q[(size_t)n * 64 + lane] = aq;
    ks[wave][lane] = ak;
    vs[wave][lane] = av;
  }
  __syncthreads();

  if (valid) {
    const int hh = lane >> 4;
    const int f = lane & 15;
#pragma unroll
    for (int et = 0; et < ET_TYPES; ++et) {
      const float* ra = Ratt + ((size_t)(hh * ET_TYPES + et)) * 256;
      const float* rm = Rmsg + ((size_t)(hh * ET_TYPES + et)) * 256;
      float sa = 0.f, sm = 0.f;
#pragma unroll
      for (int d0 = 0; d0 < 16; ++d0) {
        float kd = ks[wave][hh * 16 + d0];
        float vd = vs[wave][hh * 16 + d0];
        sa = fmaf(kd, ra[d0 * 16 + f], sa);
        sm = fmaf(vd, rm[d0 * 16 + f], sm);
      }
      kv[((size_t)et * N_NODES + n) * 64 + lane] = make_float2(sa, sm);
    }
  }
}

// ---------------------------------------------------------------------------
// CSR build: count degrees, 3-kernel scan, fill packed edge records.
// ---------------------------------------------------------------------------
__global__ void count_deg_kernel(const int* __restrict__ dst, int* __restrict__ deg) {
  int e = blockIdx.x * 256 + threadIdx.x;
  if (e < N_EDGES) atomicAdd(&deg[dst[e]], 1);
}

__global__ void block_sums_kernel(const int* __restrict__ deg, int* __restrict__ bsums) {
  __shared__ int sh[256];
  int i = blockIdx.x * 256 + threadIdx.x;
  sh[threadIdx.x] = (i < N_NODES) ? deg[i] : 0;
  __syncthreads();
  for (int off = 128; off > 0; off >>= 1) {
    if (threadIdx.x < off) sh[threadIdx.x] += sh[threadIdx.x + off];
    __syncthreads();
  }
  if (threadIdx.x == 0) bsums[blockIdx.x] = sh[0];
}

__global__ void scan_sums_kernel(int* __restrict__ bsums) {
  __shared__ int sh[256];
  int t = threadIdx.x;
  sh[t] = (t < NB_SCAN) ? bsums[t] : 0;
  __syncthreads();
  for (int off = 1; off < 256; off <<= 1) {
    int v = (t >= off) ? sh[t - off] : 0;
    __syncthreads();
    sh[t] += v;
    __syncthreads();
  }
  if (t < NB_SCAN) bsums[t] = (t ? sh[t - 1] : 0);  // exclusive
}

__global__ void scan_final_kernel(const int* __restrict__ deg, const int* __restrict__ bsums,
                                  int* __restrict__ rowstart, int* __restrict__ cursor) {
  __shared__ int sh[256];
  int i = blockIdx.x * 256 + threadIdx.x;
  int t = threadIdx.x;
  sh[t] = (i < N_NODES) ? deg[i] : 0;
  __syncthreads();
  for (int off = 1; off < 256; off <<= 1) {
    int v = (t >= off) ? sh[t - off] : 0;
    __syncthreads();
    sh[t] += v;
    __syncthreads();
  }
  if (i < N_NODES) {
    int excl = (t ? sh[t - 1] : 0) + bsums[blockIdx.x];
    rowstart[i] = excl;
    cursor[i] = excl;
  }
}

__global__ void fill_csr_kernel(const int* __restrict__ src, const int* __restrict__ dst,
                                const int* __restrict__ etype, int* __restrict__ cursor,
                                int* __restrict__ csr) {
  int e = blockIdx.x * 256 + threadIdx.x;
  if (e < N_EDGES) {
    int d = dst[e];
    int pos = atomicAdd(&cursor[d], 1);
    csr[pos] = src[e] | (etype[e] << 16);  // src < 65536, et in {0,1}
  }
}

// ---------------------------------------------------------------------------
// Kernel 2: per-dst-node online-softmax aggregation (4-deep pipelined gathers)
// + typed output linear + sigmoid-skip blend. One wave per node.
// ---------------------------------------------------------------------------
__device__ __forceinline__ void online_update(float2 e, int et, float qd,
                                              float p0f, float p1f,
                                              float& mrun, float& srun, float& acc) {
  float p = e.x * qd;
  p += __shfl_xor(p, 1, 16);
  p += __shfl_xor(p, 2, 16);
  p += __shfl_xor(p, 4, 16);
  p += __shfl_xor(p, 8, 16);
  float a = p * (et ? p1f : p0f);
  float nm = fmaxf(mrun, a);
  float sc = __expf(mrun - nm);     // 0 on first edge (mrun = -inf)
  float w = __expf(a - nm);
  srun = srun * sc + w;
  acc = acc * sc + e.y * w;
  mrun = nm;
}

__global__ __launch_bounds__(256) void aggregate_kernel(
    const float* __restrict__ q, const float2* __restrict__ kv,
    const float* __restrict__ x, const float* __restrict__ Wa,
    const float* __restrict__ pri, const float* __restrict__ skip,
    const int* __restrict__ ntype, const int* __restrict__ rowstart,
    const int* __restrict__ deg, const int* __restrict__ csr,
    float* __restrict__ out) {
  const int wave = threadIdx.x >> 6;
  const int lane = threadIdx.x & 63;
  const int n = blockIdx.x * 4 + wave;
  const bool valid = (n < N_NODES);

  __shared__ float hs[4][64];

  int t = 0;
  if (valid) {
    t = ntype[n];
    const int hh = lane >> 4;
    const float qd = q[(size_t)n * 64 + lane];
    const float p0f = pri[hh * ET_TYPES + 0] * 0.25f;  // /sqrt(16)
    const float p1f = pri[hh * ET_TYPES + 1] * 0.25f;
    const int start = rowstart[n];
    const int cnt = deg[n];

    float mrun = -INFINITY, srun = 0.f, acc = 0.f;
    int j = 0;
    // 4-deep pipelined main loop: 4 independent kv gathers in flight
    for (; j + 4 <= cnt; j += 4) {
      int pk0 = csr[start + j + 0];
      int pk1 = csr[start + j + 1];
      int pk2 = csr[start + j + 2];
      int pk3 = csr[start + j + 3];
      int et0 = pk0 >> 16, et1 = pk1 >> 16, et2 = pk2 >> 16, et3 = pk3 >> 16;
      float2 e0 = kv[((size_t)et0 * N_NODES + (pk0 & 0xFFFF)) * 64 + lane];
      float2 e1 = kv[((size_t)et1 * N_NODES + (pk1 & 0xFFFF)) * 64 + lane];
      float2 e2 = kv[((size_t)et2 * N_NODES + (pk2 & 0xFFFF)) * 64 + lane];
      float2 e3 = kv[((size_t)et3 * N_NODES + (pk3 & 0xFFFF)) * 64 + lane];
      online_update(e0, et0, qd, p0f, p1f, mrun, srun, acc);
      online_update(e1, et1, qd, p0f, p1f, mrun, srun, acc);
      online_update(e2, et2, qd, p0f, p1f, mrun, srun, acc);
      online_update(e3, et3, qd, p0f, p1f, mrun, srun, acc);
    }
    for (; j < cnt; ++j) {
      int pk = csr[start + j];
      int et = pk >> 16;
      float2 e = kv[((size_t)et * N_NODES + (pk & 0xFFFF)) * 64 + lane];
      online_update(e, et, qd, p0f, p1f, mrun, srun, acc);
    }
    hs[wave][lane] = (srun > 0.f) ? (acc / srun) : 0.f;
  }
  __syncthreads();

  if (valid) {
    const float* wa = Wa + (size_t)t * 4096;
    float acc2 = 0.f;
#pragma unroll 8
    for (int i = 0; i < 64; ++i) acc2 = fmaf(hs[wave][i], wa[i * 64 + lane], acc2);
    float alpha = 1.f / (1.f + __expf(-skip[t]));
    size_t o = (size_t)n * 64 + lane;
    out[o] = acc2 * alpha + x[o] * (1.f - alpha);
  }
}

// ---------------------------------------------------------------------------
extern "C" void kernel_launch(void* const* d_in, const int* in_sizes, int n_in,
                              void* d_out, int out_size, void* d_ws, size_t ws_size,
                              hipStream_t stream) {
  const float* x    = (const float*)d_in[0];
  const float* Wk   = (const float*)d_in[1];
  const float* Wq   = (const float*)d_in[2];
  const float* Wv   = (const float*)d_in[3];
  const float* Wa   = (const float*)d_in[4];
  const float* Ratt = (const float*)d_in[5];
  const float* Rmsg = (const float*)d_in[6];
  const float* pri  = (const float*)d_in[7];
  const float* skip = (const float*)d_in[8];
  const int* ntype  = (const int*)d_in[9];
  const int* etype  = (const int*)d_in[10];
  const int* src    = (const int*)d_in[11];
  const int* dst    = (const int*)d_in[12];
  float* out = (float*)d_out;

  // workspace layout
  float* q     = (float*)d_ws;                       // N*64
  float2* kv   = (float2*)(q + (size_t)N_NODES * 64); // ET*N*64 float2
  int* rowstart = (int*)(kv + (size_t)ET_TYPES * N_NODES * 64);  // N
  int* deg      = rowstart + N_NODES;                // N
  int* cursor   = deg + N_NODES;                     // N
  int* csr      = cursor + N_NODES;                  // E
  int* bsums    = csr + N_EDGES;                     // NB_SCAN

  hipMemsetAsync(deg, 0, N_NODES * sizeof(int), stream);

  node_proj_kernel<<<(N_NODES + 3) / 4, 256, 0, stream>>>(
      x, Wk, Wq, Wv, Ratt, Rmsg, ntype, q, kv);

  count_deg_kernel<<<(N_EDGES + 255) / 256, 256, 0, stream>>>(dst, deg);
  block_sums_kernel<<<NB_SCAN, 256, 0, stream>>>(deg, bsums);
  scan_sums_kernel<<<1, 256, 0, stream>>>(bsums);
  scan_final_kernel<<<NB_SCAN, 256, 0, stream>>>(deg, bsums, rowstart, cursor);
  fill_csr_kernel<<<(N_EDGES + 255) / 256, 256, 0, stream>>>(src, dst, etype, cursor, csr);

  aggregate_kernel<<<(N_NODES + 3) / 4, 256, 0, stream>>>(
      q, kv, x, Wa, pri, skip, ntype, rowstart, deg, csr, out);
}